// Round 3
// baseline (878.479 us; speedup 1.0000x reference)
//
#include <hip/hip_runtime.h>

// Problem constants (B=8, H=W=512, WIDTH=12)
constexpr int IMG = 512;
constexpr int NCH = 12;
constexpr long long OPLANE = 1024LL * 1024LL;   // one output plane (2H x 2W)

// ---------------------------------------------------------------------------
// Stage 1: fused 3-layer conv stacks (interp + weight), softmax, weighted sum.
// Writes the FULL GREEN OUTPUT PLANE of d_out directly:
//   G(2y,2x)=m0, G(2y,2x+1)=g0, G(2y+1,2x)=g1, G(2y+1,2x+1)=m3
// (exactly pixel_shuffle2 of [m0, green_rb0, green_rb1, m3])
// => no workspace needed; stage 2 reads g0/g1 back from the G plane.
// Tile: 16x16 output pixels per block, 256 threads.
// LDS: mosaic 4x22x22, L1 12x20x20, L2 12x18x18  (~42.5 KB -> 3 blocks/CU)
// ---------------------------------------------------------------------------
__global__ __launch_bounds__(256) void demosaic_stage1(
    const float* __restrict__ mosaic,
    const float* __restrict__ fw0, const float* __restrict__ fw1, const float* __restrict__ fw2,
    const float* __restrict__ ww0, const float* __restrict__ ww1, const float* __restrict__ ww2,
    float* __restrict__ out)
{
    __shared__ float s_mos[4][22][22];
    __shared__ float s_a[NCH][20][20];
    __shared__ float s_b[NCH][18][18];

    const int tid = threadIdx.x;
    const int b   = blockIdx.z;
    const int gy0 = blockIdx.y * 16;
    const int gx0 = blockIdx.x * 16;

    // ---- stage mosaic tile with halo 3 (rows gy0-3 .. gy0+18) ----
    for (int idx = tid; idx < 4 * 22 * 22; idx += 256) {
        int c = idx / 484;
        int r = idx - c * 484;
        int y = r / 22;
        int x = r - y * 22;
        int gy = gy0 - 3 + y, gx = gx0 - 3 + x;
        float v = 0.f;
        if (gy >= 0 && gy < IMG && gx >= 0 && gx < IMG)
            v = mosaic[((b * 4 + c) * IMG + gy) * IMG + gx];
        s_mos[c][y][x] = v;
    }
    __syncthreads();

    float f3[NCH];        // interp stack layer-3 output (registers)
    float g0o = 0.f, g1o = 0.f;

    #pragma unroll 1
    for (int s = 0; s < 2; ++s) {
        const float* __restrict__ w0 = s ? ww0 : fw0;
        const float* __restrict__ w1 = s ? ww1 : fw1;
        const float* __restrict__ w2 = s ? ww2 : fw2;
        if (s) __syncthreads();   // protect s_a/s_b reuse across stacks

        // ---- Layer 1: 4 -> 12 on 20x20 region (mosaic coords gy0-2 .. gy0+17)
        #pragma unroll 1
        for (int it = 0; it < 2; ++it) {
            int px = tid + it * 256;
            if (px < 400) {
                int y = px / 20, x = px - y * 20;
                float acc[NCH];
                #pragma unroll
                for (int k = 0; k < NCH; ++k) acc[k] = 0.f;
                #pragma unroll
                for (int c = 0; c < 4; ++c)
                    #pragma unroll
                    for (int dy = 0; dy < 3; ++dy)
                        #pragma unroll
                        for (int dx = 0; dx < 3; ++dx) {
                            float v = s_mos[c][y + dy][x + dx];
                            #pragma unroll
                            for (int k = 0; k < NCH; ++k)
                                acc[k] = fmaf(v, w0[(k * 4 + c) * 9 + dy * 3 + dx], acc[k]);
                        }
                int gy = gy0 - 2 + y, gx = gx0 - 2 + x;
                bool inb = (gy >= 0 && gy < IMG && gx >= 0 && gx < IMG);
                #pragma unroll
                for (int k = 0; k < NCH; ++k)
                    s_a[k][y][x] = inb ? fmaxf(acc[k], 0.f) : 0.f;  // zero == conv pad
            }
        }
        __syncthreads();

        // ---- Layer 2: 12 -> 12 on 18x18 region (coords gy0-1 .. gy0+16)
        #pragma unroll 1
        for (int it = 0; it < 2; ++it) {
            int px = tid + it * 256;
            if (px < 324) {
                int y = px / 18, x = px - y * 18;
                float acc[NCH];
                #pragma unroll
                for (int k = 0; k < NCH; ++k) acc[k] = 0.f;
                #pragma unroll 1
                for (int c = 0; c < NCH; ++c)
                    #pragma unroll
                    for (int dy = 0; dy < 3; ++dy)
                        #pragma unroll
                        for (int dx = 0; dx < 3; ++dx) {
                            float v = s_a[c][y + dy][x + dx];
                            #pragma unroll
                            for (int k = 0; k < NCH; ++k)
                                acc[k] = fmaf(v, w1[(k * NCH + c) * 9 + dy * 3 + dx], acc[k]);
                        }
                int gy = gy0 - 1 + y, gx = gx0 - 1 + x;
                bool inb = (gy >= 0 && gy < IMG && gx >= 0 && gx < IMG);
                #pragma unroll
                for (int k = 0; k < NCH; ++k)
                    s_b[k][y][x] = inb ? fmaxf(acc[k], 0.f) : 0.f;
            }
        }
        __syncthreads();

        // ---- Layer 3: 12 -> 12 on the 16x16 tile, one pixel per thread
        {
            int ty = tid >> 4, tx = tid & 15;
            float acc[NCH];
            #pragma unroll
            for (int k = 0; k < NCH; ++k) acc[k] = 0.f;
            #pragma unroll 1
            for (int c = 0; c < NCH; ++c)
                #pragma unroll
                for (int dy = 0; dy < 3; ++dy)
                    #pragma unroll
                    for (int dx = 0; dx < 3; ++dx) {
                        float v = s_b[c][ty + dy][tx + dx];
                        #pragma unroll
                        for (int k = 0; k < NCH; ++k)
                            acc[k] = fmaf(v, w2[(k * NCH + c) * 9 + dy * 3 + dx], acc[k]);
                    }
            if (s == 0) {
                #pragma unroll
                for (int k = 0; k < NCH; ++k) f3[k] = fmaxf(acc[k], 0.f);
            } else {
                // softmax over relu(acc), then weighted sums (ch 0-5 -> g0, 6-11 -> g1)
                float wv[NCH];
                float m = 0.f;                       // relu output >= 0, so 0 is a safe max-init
                #pragma unroll
                for (int k = 0; k < NCH; ++k) { wv[k] = fmaxf(acc[k], 0.f); m = fmaxf(m, wv[k]); }
                float denom = 0.f, a0 = 0.f, a1 = 0.f;
                #pragma unroll
                for (int k = 0; k < NCH; ++k) {
                    float e = __expf(wv[k] - m);     // v_exp_f32 path; softmax is shift-invariant
                    denom += e;
                    if (k < 6) a0 = fmaf(f3[k], e, a0);
                    else       a1 = fmaf(f3[k], e, a1);
                }
                float inv = 1.f / denom;
                g0o = a0 * inv;
                g1o = a1 * inv;
            }
        }
    }

    // ---- write G plane of the output directly (pixel-shuffled quad) ----
    const int ty = tid >> 4, tx = tid & 15;
    const int gy = gy0 + ty, gx = gx0 + tx;
    const float m0 = s_mos[0][ty + 3][tx + 3];   // mosaic(gy,gx) ch0, already in LDS
    const float m3 = s_mos[3][ty + 3][tx + 3];

    float* gpl = out + (long long)(b * 3 + 1) * OPLANE;
    *reinterpret_cast<float2*>(&gpl[(long long)(2 * gy) * 1024 + 2 * gx])     = make_float2(m0, g0o);
    *reinterpret_cast<float2*>(&gpl[(long long)(2 * gy + 1) * 1024 + 2 * gx]) = make_float2(g1o, m3);
}

// ---------------------------------------------------------------------------
// Stage 2: chroma 5x5 convs + interleave -> R and B planes.
// chroma_input == 0 at (even,even) and (odd,odd) flat sites:
//   chroma(2h,2w)     = m0 - m0 = 0
//   chroma(2h,2w+1)   = m1 - g0   (c1)
//   chroma(2h+1,2w)   = m2 - g1   (c2)
//   chroma(2h+1,2w+1) = m3 - m3 = 0
// Each quad needs only: ch@(ee,oo), cv@(ee,oo), cq@(eo,oe) -> 6 evals, ~12 taps each.
// g0/g1 are read back from the G plane written by stage 1.
// ---------------------------------------------------------------------------
template <int PI, int PJ>
__device__ __forceinline__ float conv5(const float (&c1s)[18][18], const float (&c2s)[18][18],
                                       const float* __restrict__ w, int ly, int lx)
{
    float acc = 0.f;
    #pragma unroll
    for (int ky = 0; ky < 5; ++ky) {
        const int fy = PI + ky - 2;          // flat row offset from 2*quad
        const int qy = (fy - (fy & 1)) / 2;  // floor div 2 (compile-time after unroll)
        const int ry = fy & 1;
        #pragma unroll
        for (int kx = 0; kx < 5; ++kx) {
            const int fx = PJ + kx - 2;
            const int qx = (fx - (fx & 1)) / 2;
            const int rx = fx & 1;
            if (ry == 0 && rx == 1)
                acc = fmaf(c1s[ly + qy][lx + qx], w[ky * 5 + kx], acc);
            else if (ry == 1 && rx == 0)
                acc = fmaf(c2s[ly + qy][lx + qx], w[ky * 5 + kx], acc);
            // else: chroma_input structurally zero -> skip
        }
    }
    return acc;
}

__global__ __launch_bounds__(256) void demosaic_stage2(
    const float* __restrict__ mosaic,
    const float* gplane,                     // aliases `out` (G plane) - no restrict
    const float* __restrict__ chw, const float* __restrict__ cvw, const float* __restrict__ cqw,
    float* out)
{
    __shared__ float c1s[18][18];
    __shared__ float c2s[18][18];

    const int tid = threadIdx.x;
    const int b   = blockIdx.z;
    const int qy0 = blockIdx.y * 16;
    const int qx0 = blockIdx.x * 16;

    const float* gpl = gplane + (long long)(b * 3 + 1) * OPLANE;

    // stage c1/c2 for 18x18 quads (halo 1), zero outside image (conv zero-pad)
    for (int idx = tid; idx < 324; idx += 256) {
        int y = idx / 18, x = idx - y * 18;
        int gy = qy0 - 1 + y, gx = qx0 - 1 + x;
        float v1 = 0.f, v2 = 0.f;
        if (gy >= 0 && gy < IMG && gx >= 0 && gx < IMG) {
            float m1 = mosaic[((b * 4 + 1) * IMG + gy) * IMG + gx];
            float m2 = mosaic[((b * 4 + 2) * IMG + gy) * IMG + gx];
            // coalesced float2 reads of the G plane: (ee,eo) and (oe,oo)
            float2 ta = *reinterpret_cast<const float2*>(&gpl[(long long)(2 * gy) * 1024 + 2 * gx]);
            float2 tb = *reinterpret_cast<const float2*>(&gpl[(long long)(2 * gy + 1) * 1024 + 2 * gx]);
            v1 = m1 - ta.y;   // m1 - g0
            v2 = m2 - tb.x;   // m2 - g1
        }
        c1s[y][x] = v1;
        c2s[y][x] = v2;
    }
    __syncthreads();

    const int ty = tid >> 4, tx = tid & 15;
    const int qy = qy0 + ty, qx = qx0 + tx;
    const int ly = ty + 1, lx = tx + 1;

    // center quad values: m0,g0 / g1,m3 from the G plane (float2), m1/m2 from mosaic
    const float2 t0 = *reinterpret_cast<const float2*>(&gpl[(long long)(2 * qy) * 1024 + 2 * qx]);
    const float2 t1 = *reinterpret_cast<const float2*>(&gpl[(long long)(2 * qy + 1) * 1024 + 2 * qx]);
    const float m0 = t0.x, g0 = t0.y, g1 = t1.x, m3 = t1.y;
    const float m1 = mosaic[((b * 4 + 1) * IMG + qy) * IMG + qx];
    const float m2 = mosaic[((b * 4 + 2) * IMG + qy) * IMG + qx];

    const float ch_ee = conv5<0, 0>(c1s, c2s, chw, ly, lx);
    const float ch_oo = conv5<1, 1>(c1s, c2s, chw, ly, lx);
    const float cv_ee = conv5<0, 0>(c1s, c2s, cvw, ly, lx);
    const float cv_oo = conv5<1, 1>(c1s, c2s, cvw, ly, lx);
    const float cq_eo = conv5<0, 1>(c1s, c2s, cqw, ly, lx);
    const float cq_oe = conv5<1, 0>(c1s, c2s, cqw, ly, lx);

    // ch/cv/cq have "+ flat_green" fused:  flat_green (ee)=m0, (eo)=g0, (oe)=g1, (oo)=m3
    const float r00 = ch_ee + m0, r01 = m1,         r10 = cq_oe + g1, r11 = cv_oo + m3;
    const float b00 = cv_ee + m0, b01 = cq_eo + g0, b10 = m2,         b11 = ch_oo + m3;

    const int ys = 2 * qy, xs = 2 * qx;
    float* outR = out + (long long)(b * 3 + 0) * OPLANE;
    float* outB = out + (long long)(b * 3 + 2) * OPLANE;

    *reinterpret_cast<float2*>(&outR[(long long)ys * 1024 + xs])       = make_float2(r00, r01);
    *reinterpret_cast<float2*>(&outR[(long long)(ys + 1) * 1024 + xs]) = make_float2(r10, r11);
    *reinterpret_cast<float2*>(&outB[(long long)ys * 1024 + xs])       = make_float2(b00, b01);
    *reinterpret_cast<float2*>(&outB[(long long)(ys + 1) * 1024 + xs]) = make_float2(b10, b11);
}

extern "C" void kernel_launch(void* const* d_in, const int* in_sizes, int n_in,
                              void* d_out, int out_size, void* d_ws, size_t ws_size,
                              hipStream_t stream)
{
    const float* mosaic = (const float*)d_in[0];
    const float* fw0 = (const float*)d_in[1];
    const float* fw1 = (const float*)d_in[2];
    const float* fw2 = (const float*)d_in[3];
    const float* ww0 = (const float*)d_in[4];
    const float* ww1 = (const float*)d_in[5];
    const float* ww2 = (const float*)d_in[6];
    const float* chw = (const float*)d_in[7];
    const float* cvw = (const float*)d_in[8];
    const float* cqw = (const float*)d_in[9];

    float* out = (float*)d_out;            // [8][3][1024][1024] fp32

    dim3 grid(IMG / 16, IMG / 16, 8);      // 32 x 32 x 8
    demosaic_stage1<<<grid, 256, 0, stream>>>(mosaic, fw0, fw1, fw2, ww0, ww1, ww2, out);
    demosaic_stage2<<<grid, 256, 0, stream>>>(mosaic, out, chw, cvw, cqw, out);
}

// Round 4
// 791.678 us; speedup vs baseline: 1.1096x; 1.1096x over previous
//
#include <hip/hip_runtime.h>

// Problem constants (B=8, H=W=512, WIDTH=12)
constexpr int IMG = 512;
constexpr int NCH = 12;
constexpr long long OPLANE = 1024LL * 1024LL;   // one output plane (2H x 2W)

// ---------------------------------------------------------------------------
// Stage 1: fused 3-layer conv stacks (interp + weight), softmax, weighted sum.
// Writes the FULL GREEN OUTPUT PLANE of d_out directly:
//   G(2y,2x)=m0, G(2y,2x+1)=g0, G(2y+1,2x)=g1, G(2y+1,2x+1)=m3
// Tile: 16x16 output px / block, 256 threads.
//
// R3 change (occupancy): layer-1 runs in TWO 6-channel passes through a
// half-size s_a; layer-2 accumulates partial sums in s_b (identical fp32
// add order -> bit-identical numerics). LDS 42.5KB -> 33.8KB = 4 blocks/CU.
// All LDS arrays padded to odd strides (23/21/19) to break bank aliasing.
// ---------------------------------------------------------------------------
__global__ __launch_bounds__(256) void demosaic_stage1(
    const float* __restrict__ mosaic,
    const float* __restrict__ fw0, const float* __restrict__ fw1, const float* __restrict__ fw2,
    const float* __restrict__ ww0, const float* __restrict__ ww1, const float* __restrict__ ww2,
    float* __restrict__ out)
{
    __shared__ float s_mos[4][22][23];   // mosaic tile, halo 3
    __shared__ float s_a[6][20][21];     // layer-1 output, ONE 6-channel half
    __shared__ float s_b[NCH][18][19];   // layer-2 output (all 12 ch)

    const int tid = threadIdx.x;
    const int b   = blockIdx.z;
    const int gy0 = blockIdx.y * 16;
    const int gx0 = blockIdx.x * 16;

    // ---- stage mosaic tile with halo 3 (rows gy0-3 .. gy0+18) ----
    for (int idx = tid; idx < 4 * 22 * 22; idx += 256) {
        int c = idx / 484;
        int r = idx - c * 484;
        int y = r / 22;
        int x = r - y * 22;
        int gy = gy0 - 3 + y, gx = gx0 - 3 + x;
        float v = 0.f;
        if (gy >= 0 && gy < IMG && gx >= 0 && gx < IMG)
            v = mosaic[((b * 4 + c) * IMG + gy) * IMG + gx];
        s_mos[c][y][x] = v;
    }
    __syncthreads();

    float f3[NCH];        // interp stack layer-3 output (registers)
    float g0o = 0.f, g1o = 0.f;

    #pragma unroll 1
    for (int s = 0; s < 2; ++s) {
        const float* __restrict__ w0 = s ? ww0 : fw0;
        const float* __restrict__ w1 = s ? ww1 : fw1;
        const float* __restrict__ w2 = s ? ww2 : fw2;

        // ---- Layers 1+2 in two 6-channel halves ----
        #pragma unroll 1
        for (int half = 0; half < 2; ++half) {
            // Layer 1 (6 out-channels): 4 -> 6 on 20x20 (mosaic coords gy0-2..gy0+17)
            #pragma unroll 1
            for (int it = 0; it < 2; ++it) {
                int px = tid + it * 256;
                if (px < 400) {
                    int y = px / 20, x = px - y * 20;
                    float acc[6];
                    #pragma unroll
                    for (int k = 0; k < 6; ++k) acc[k] = 0.f;
                    #pragma unroll
                    for (int c = 0; c < 4; ++c)
                        #pragma unroll
                        for (int dy = 0; dy < 3; ++dy)
                            #pragma unroll
                            for (int dx = 0; dx < 3; ++dx) {
                                float v = s_mos[c][y + dy][x + dx];
                                #pragma unroll
                                for (int k = 0; k < 6; ++k)
                                    acc[k] = fmaf(v, w0[((half * 6 + k) * 4 + c) * 9 + dy * 3 + dx], acc[k]);
                            }
                    int gy = gy0 - 2 + y, gx = gx0 - 2 + x;
                    bool inb = (gy >= 0 && gy < IMG && gx >= 0 && gx < IMG);
                    #pragma unroll
                    for (int k = 0; k < 6; ++k)
                        s_a[k][y][x] = inb ? fmaxf(acc[k], 0.f) : 0.f;  // zero == conv pad
                }
            }
            __syncthreads();

            // Layer 2 partial: accumulate 6 input channels into all 12 outputs, 18x18
            #pragma unroll 1
            for (int it = 0; it < 2; ++it) {
                int px = tid + it * 256;
                if (px < 324) {
                    int y = px / 18, x = px - y * 18;
                    float acc[NCH];
                    if (half == 0) {
                        #pragma unroll
                        for (int k = 0; k < NCH; ++k) acc[k] = 0.f;
                    } else {
                        #pragma unroll
                        for (int k = 0; k < NCH; ++k) acc[k] = s_b[k][y][x];  // raw partials
                    }
                    #pragma unroll 1
                    for (int c = 0; c < 6; ++c)
                        #pragma unroll
                        for (int dy = 0; dy < 3; ++dy)
                            #pragma unroll
                            for (int dx = 0; dx < 3; ++dx) {
                                float v = s_a[c][y + dy][x + dx];
                                #pragma unroll
                                for (int k = 0; k < NCH; ++k)
                                    acc[k] = fmaf(v, w1[(k * NCH + half * 6 + c) * 9 + dy * 3 + dx], acc[k]);
                            }
                    if (half == 0) {
                        #pragma unroll
                        for (int k = 0; k < NCH; ++k) s_b[k][y][x] = acc[k];  // raw, no relu yet
                    } else {
                        int gy = gy0 - 1 + y, gx = gx0 - 1 + x;
                        bool inb = (gy >= 0 && gy < IMG && gx >= 0 && gx < IMG);
                        #pragma unroll
                        for (int k = 0; k < NCH; ++k)
                            s_b[k][y][x] = inb ? fmaxf(acc[k], 0.f) : 0.f;
                    }
                }
            }
            __syncthreads();
        }

        // ---- Layer 3: 12 -> 12 on the 16x16 tile, one pixel per thread ----
        // (no trailing barrier needed: next writes to s_a/s_b sit behind the
        //  next half's __syncthreads)
        {
            int ty = tid >> 4, tx = tid & 15;
            float acc[NCH];
            #pragma unroll
            for (int k = 0; k < NCH; ++k) acc[k] = 0.f;
            #pragma unroll 1
            for (int c = 0; c < NCH; ++c)
                #pragma unroll
                for (int dy = 0; dy < 3; ++dy)
                    #pragma unroll
                    for (int dx = 0; dx < 3; ++dx) {
                        float v = s_b[c][ty + dy][tx + dx];
                        #pragma unroll
                        for (int k = 0; k < NCH; ++k)
                            acc[k] = fmaf(v, w2[(k * NCH + c) * 9 + dy * 3 + dx], acc[k]);
                    }
            if (s == 0) {
                #pragma unroll
                for (int k = 0; k < NCH; ++k) f3[k] = fmaxf(acc[k], 0.f);
            } else {
                // softmax over relu(acc), then weighted sums (ch 0-5 -> g0, 6-11 -> g1)
                float wv[NCH];
                float m = 0.f;                       // relu output >= 0, safe max-init
                #pragma unroll
                for (int k = 0; k < NCH; ++k) { wv[k] = fmaxf(acc[k], 0.f); m = fmaxf(m, wv[k]); }
                float denom = 0.f, a0 = 0.f, a1 = 0.f;
                #pragma unroll
                for (int k = 0; k < NCH; ++k) {
                    float e = __expf(wv[k] - m);     // v_exp_f32; softmax shift-invariant
                    denom += e;
                    if (k < 6) a0 = fmaf(f3[k], e, a0);
                    else       a1 = fmaf(f3[k], e, a1);
                }
                float inv = 1.f / denom;
                g0o = a0 * inv;
                g1o = a1 * inv;
            }
        }
    }

    // ---- write G plane of the output directly (pixel-shuffled quad) ----
    const int ty = tid >> 4, tx = tid & 15;
    const int gy = gy0 + ty, gx = gx0 + tx;
    const float m0 = s_mos[0][ty + 3][tx + 3];   // mosaic(gy,gx) ch0, already in LDS
    const float m3 = s_mos[3][ty + 3][tx + 3];

    float* gpl = out + (long long)(b * 3 + 1) * OPLANE;
    *reinterpret_cast<float2*>(&gpl[(long long)(2 * gy) * 1024 + 2 * gx])     = make_float2(m0, g0o);
    *reinterpret_cast<float2*>(&gpl[(long long)(2 * gy + 1) * 1024 + 2 * gx]) = make_float2(g1o, m3);
}

// ---------------------------------------------------------------------------
// Stage 2: chroma 5x5 convs + interleave -> R and B planes.  (unchanged)
// chroma_input == 0 at (even,even) and (odd,odd) flat sites.
// ---------------------------------------------------------------------------
template <int PI, int PJ>
__device__ __forceinline__ float conv5(const float (&c1s)[18][18], const float (&c2s)[18][18],
                                       const float* __restrict__ w, int ly, int lx)
{
    float acc = 0.f;
    #pragma unroll
    for (int ky = 0; ky < 5; ++ky) {
        const int fy = PI + ky - 2;          // flat row offset from 2*quad
        const int qy = (fy - (fy & 1)) / 2;  // floor div 2 (compile-time after unroll)
        const int ry = fy & 1;
        #pragma unroll
        for (int kx = 0; kx < 5; ++kx) {
            const int fx = PJ + kx - 2;
            const int qx = (fx - (fx & 1)) / 2;
            const int rx = fx & 1;
            if (ry == 0 && rx == 1)
                acc = fmaf(c1s[ly + qy][lx + qx], w[ky * 5 + kx], acc);
            else if (ry == 1 && rx == 0)
                acc = fmaf(c2s[ly + qy][lx + qx], w[ky * 5 + kx], acc);
            // else: chroma_input structurally zero -> skip
        }
    }
    return acc;
}

__global__ __launch_bounds__(256) void demosaic_stage2(
    const float* __restrict__ mosaic,
    const float* gplane,                     // aliases `out` (G plane) - no restrict
    const float* __restrict__ chw, const float* __restrict__ cvw, const float* __restrict__ cqw,
    float* out)
{
    __shared__ float c1s[18][18];
    __shared__ float c2s[18][18];

    const int tid = threadIdx.x;
    const int b   = blockIdx.z;
    const int qy0 = blockIdx.y * 16;
    const int qx0 = blockIdx.x * 16;

    const float* gpl = gplane + (long long)(b * 3 + 1) * OPLANE;

    // stage c1/c2 for 18x18 quads (halo 1), zero outside image (conv zero-pad)
    for (int idx = tid; idx < 324; idx += 256) {
        int y = idx / 18, x = idx - y * 18;
        int gy = qy0 - 1 + y, gx = qx0 - 1 + x;
        float v1 = 0.f, v2 = 0.f;
        if (gy >= 0 && gy < IMG && gx >= 0 && gx < IMG) {
            float m1 = mosaic[((b * 4 + 1) * IMG + gy) * IMG + gx];
            float m2 = mosaic[((b * 4 + 2) * IMG + gy) * IMG + gx];
            float2 ta = *reinterpret_cast<const float2*>(&gpl[(long long)(2 * gy) * 1024 + 2 * gx]);
            float2 tb = *reinterpret_cast<const float2*>(&gpl[(long long)(2 * gy + 1) * 1024 + 2 * gx]);
            v1 = m1 - ta.y;   // m1 - g0
            v2 = m2 - tb.x;   // m2 - g1
        }
        c1s[y][x] = v1;
        c2s[y][x] = v2;
    }
    __syncthreads();

    const int ty = tid >> 4, tx = tid & 15;
    const int qy = qy0 + ty, qx = qx0 + tx;
    const int ly = ty + 1, lx = tx + 1;

    const float2 t0 = *reinterpret_cast<const float2*>(&gpl[(long long)(2 * qy) * 1024 + 2 * qx]);
    const float2 t1 = *reinterpret_cast<const float2*>(&gpl[(long long)(2 * qy + 1) * 1024 + 2 * qx]);
    const float m0 = t0.x, g0 = t0.y, g1 = t1.x, m3 = t1.y;
    const float m1 = mosaic[((b * 4 + 1) * IMG + qy) * IMG + qx];
    const float m2 = mosaic[((b * 4 + 2) * IMG + qy) * IMG + qx];

    const float ch_ee = conv5<0, 0>(c1s, c2s, chw, ly, lx);
    const float ch_oo = conv5<1, 1>(c1s, c2s, chw, ly, lx);
    const float cv_ee = conv5<0, 0>(c1s, c2s, cvw, ly, lx);
    const float cv_oo = conv5<1, 1>(c1s, c2s, cvw, ly, lx);
    const float cq_eo = conv5<0, 1>(c1s, c2s, cqw, ly, lx);
    const float cq_oe = conv5<1, 0>(c1s, c2s, cqw, ly, lx);

    // ch/cv/cq have "+ flat_green" fused:  flat_green (ee)=m0, (eo)=g0, (oe)=g1, (oo)=m3
    const float r00 = ch_ee + m0, r01 = m1,         r10 = cq_oe + g1, r11 = cv_oo + m3;
    const float b00 = cv_ee + m0, b01 = cq_eo + g0, b10 = m2,         b11 = ch_oo + m3;

    const int ys = 2 * qy, xs = 2 * qx;
    float* outR = out + (long long)(b * 3 + 0) * OPLANE;
    float* outB = out + (long long)(b * 3 + 2) * OPLANE;

    *reinterpret_cast<float2*>(&outR[(long long)ys * 1024 + xs])       = make_float2(r00, r01);
    *reinterpret_cast<float2*>(&outR[(long long)(ys + 1) * 1024 + xs]) = make_float2(r10, r11);
    *reinterpret_cast<float2*>(&outB[(long long)ys * 1024 + xs])       = make_float2(b00, b01);
    *reinterpret_cast<float2*>(&outB[(long long)(ys + 1) * 1024 + xs]) = make_float2(b10, b11);
}

extern "C" void kernel_launch(void* const* d_in, const int* in_sizes, int n_in,
                              void* d_out, int out_size, void* d_ws, size_t ws_size,
                              hipStream_t stream)
{
    const float* mosaic = (const float*)d_in[0];
    const float* fw0 = (const float*)d_in[1];
    const float* fw1 = (const float*)d_in[2];
    const float* fw2 = (const float*)d_in[3];
    const float* ww0 = (const float*)d_in[4];
    const float* ww1 = (const float*)d_in[5];
    const float* ww2 = (const float*)d_in[6];
    const float* chw = (const float*)d_in[7];
    const float* cvw = (const float*)d_in[8];
    const float* cqw = (const float*)d_in[9];

    float* out = (float*)d_out;            // [8][3][1024][1024] fp32

    dim3 grid(IMG / 16, IMG / 16, 8);      // 32 x 32 x 8
    demosaic_stage1<<<grid, 256, 0, stream>>>(mosaic, fw0, fw1, fw2, ww0, ww1, ww2, out);
    demosaic_stage2<<<grid, 256, 0, stream>>>(mosaic, out, chw, cvw, cqw, out);
}

// Round 5
// 590.563 us; speedup vs baseline: 1.4875x; 1.3405x over previous
//
#include <hip/hip_runtime.h>
#include <hip/hip_bf16.h>

constexpr int IMG = 512;
constexpr long long OPLANE = 1024LL * 1024LL;   // one output plane (2H x 2W)

typedef __attribute__((ext_vector_type(8))) short   short8v;   // 8 bf16 (4 VGPR) MFMA frag
typedef __attribute__((ext_vector_type(4))) float   float4v;   // MFMA C/D frag
typedef __attribute__((ext_vector_type(4))) unsigned int uint4v;

// ---- LDS carve (bytes) ----
// mosaic  [22][22][8ch] bf16 hi @0 (7744), lo @+7744
// actA  [2pl][20][20][8] hi @15488 (12800), lo @+12800   (L1 out, 12ch in 2 planes)
// actB  [2pl][18][18][8] hi @41088 (10368), lo @+10368   (L2 out)
#define MOS_LO  7744
#define A_H     15488
#define A_LO    12800
#define A_PL    6400
#define B_H     41088
#define B_LO    10368
#define B_PL    5184
#define LDS_BYTES 61824

__device__ __forceinline__ unsigned short f2bf(float v) {
    __hip_bfloat16 h = __float2bfloat16(v);
    return *reinterpret_cast<unsigned short*>(&h);
}
__device__ __forceinline__ float bf2f(unsigned short u) {
    __hip_bfloat16 h = *reinterpret_cast<__hip_bfloat16*>(&u);
    return __bfloat162float(h);
}

// byte offset in the activation array for conv tap t (3x3 raster), 0 for padded taps
__device__ __forceinline__ int tapoff(int t, int rowBytes) {
    if (t >= 9) return 0;
    int dy = t / 3;
    int dx = t - 3 * dy;
    return dy * rowBytes + dx * 16;
}

// Build A-fragments (weights) hi/lo for one layer, per k-step.
// K-slot mapping (k = 8*g + e, g = lane>>4):
//   QUAD (L1):  tap = 4*ks + g,        ch = e          (valid: ch<INC, tap<9)
//   PAIR (L2/3):tap = 2*ks + (g>>1),   ch = (g&1)*8+e  (valid: ch<INC, tap<9)
// A row = lane&15 (out-channel; rows >= 12 zero).
template<int NK, bool QUAD, int INC>
__device__ __forceinline__ void build_afrags(const float* __restrict__ w, int row, int g,
                                             short8v* Ah, short8v* Al)
{
    #pragma unroll
    for (int ks = 0; ks < NK; ++ks) {
        short8v ah, al;
        #pragma unroll
        for (int e = 0; e < 8; ++e) {
            int tap = QUAD ? (4 * ks + g) : (2 * ks + (g >> 1));
            int ch  = QUAD ? e : ((g & 1) * 8 + e);
            bool valid = (row < 12) && (ch < INC) && (tap < 9);
            int idx = valid ? (row * INC + ch) * 9 + tap : 0;
            float v = w[idx];
            v = valid ? v : 0.f;
            unsigned short hs = f2bf(v);
            float lo = v - bf2f(hs);
            ah[e] = (short)hs;
            al[e] = (short)f2bf(lo);
        }
        Ah[ks] = ah; Al[ks] = al;
    }
}

// Accumulate one 16(out-ch) x 16(px) tile: per k-step read Bh/Bl (one b128 each)
// and chain 3 split-MFMAs into the same accumulator.
template<int NK, int LO>
__device__ __forceinline__ float4v mfma_tile(const char* bbase, const int* voff,
                                             const short8v* Ah, const short8v* Al)
{
    float4v acc = {0.f, 0.f, 0.f, 0.f};
    #pragma unroll
    for (int ks = 0; ks < NK; ++ks) {
        const char* p = bbase + voff[ks];
        short8v bh = *reinterpret_cast<const short8v*>(p);
        short8v bl = *reinterpret_cast<const short8v*>(p + LO);
        acc = __builtin_amdgcn_mfma_f32_16x16x32_bf16(Ah[ks], bh, acc, 0, 0, 0);
        acc = __builtin_amdgcn_mfma_f32_16x16x32_bf16(Ah[ks], bl, acc, 0, 0, 0);
        acc = __builtin_amdgcn_mfma_f32_16x16x32_bf16(Al[ks], bh, acc, 0, 0, 0);
    }
    return acc;
}

// relu(+bound-zero), split to bf16 hi/lo, write 4 channels (8B hi + 8B lo)
__device__ __forceinline__ void write_hl(char* dst, int loOff, float4v acc, bool inb)
{
    unsigned long long hw = 0, lw = 0;
    #pragma unroll
    for (int r = 0; r < 4; ++r) {
        float v = inb ? fmaxf(acc[r], 0.f) : 0.f;
        unsigned short hs = f2bf(v);
        float lo = v - bf2f(hs);
        unsigned short ls = f2bf(lo);
        hw |= (unsigned long long)hs << (16 * r);
        lw |= (unsigned long long)ls << (16 * r);
    }
    *reinterpret_cast<unsigned long long*>(dst) = hw;
    *reinterpret_cast<unsigned long long*>(dst + loOff) = lw;
}

// ---------------------------------------------------------------------------
// Stage 1 (MFMA): 3-layer conv stacks as hi/lo-split bf16 GEMMs.
// 16x16 tile / block, 256 threads (4 waves share the n-tiles of each layer).
// Writes the G output plane directly: G(2y,2x)=m0, (2y,2x+1)=g0, (2y+1,2x)=g1,
// (2y+1,2x+1)=m3.
// ---------------------------------------------------------------------------
__global__ __launch_bounds__(256) void demosaic_stage1(
    const float* __restrict__ mosaic,
    const float* __restrict__ fw0, const float* __restrict__ fw1, const float* __restrict__ fw2,
    const float* __restrict__ ww0, const float* __restrict__ ww1, const float* __restrict__ ww2,
    float* __restrict__ out)
{
    __shared__ __align__(16) char lds[LDS_BYTES];
    const int tid  = threadIdx.x;
    const int lane = tid & 63;
    const int wave = tid >> 6;
    const int l16  = lane & 15;
    const int g    = lane >> 4;
    const int b    = blockIdx.z;
    const int gy0  = blockIdx.y * 16;
    const int gx0  = blockIdx.x * 16;

    // ---- stage mosaic (halo 3) as bf16 hi/lo: [22][22][8ch] (ch4-7 zero) ----
    for (int idx = tid; idx < 484; idx += 256) {
        int y = idx / 22, x = idx - 22 * y;
        int gy = gy0 - 3 + y, gx = gx0 - 3 + x;
        bool inb = (gy >= 0 && gy < IMG && gx >= 0 && gx < IMG);
        unsigned short hs[4], ls[4];
        #pragma unroll
        for (int c = 0; c < 4; ++c) {
            float m = inb ? mosaic[((b * 4 + c) * IMG + gy) * IMG + gx] : 0.f;
            hs[c] = f2bf(m);
            ls[c] = f2bf(m - bf2f(hs[c]));
        }
        uint4v hv = { (unsigned)hs[0] | ((unsigned)hs[1] << 16),
                      (unsigned)hs[2] | ((unsigned)hs[3] << 16), 0u, 0u };
        uint4v lv = { (unsigned)ls[0] | ((unsigned)ls[1] << 16),
                      (unsigned)ls[2] | ((unsigned)ls[3] << 16), 0u, 0u };
        char* dst = lds + (y * 22 + x) * 16;
        *reinterpret_cast<uint4v*>(dst)          = hv;
        *reinterpret_cast<uint4v*>(dst + MOS_LO) = lv;
    }
    __syncthreads();

    float f3[4][4];           // interp-stack L3 outputs (4 ch per lane x 4 tiles)
    #pragma unroll 1
    for (int s = 0; s < 2; ++s) {
        const float* __restrict__ w0 = s ? ww0 : fw0;
        const float* __restrict__ w1 = s ? ww1 : fw1;
        const float* __restrict__ w2 = s ? ww2 : fw2;

        // ========== L1: mosaic(4ch) -> actA(12ch), region 20x20 (quad-tap K) ==========
        {
            short8v Ah[3], Al[3];
            build_afrags<3, true, 4>(w0, l16, g, Ah, Al);
            int voff[3];
            #pragma unroll
            for (int ks = 0; ks < 3; ++ks) voff[ks] = tapoff(4 * ks + g, 22 * 16);
            const int plOut = (g >> 1) * A_PL + (g & 1) * 8;
            for (int t = wave; t < 25; t += 4) {           // 400 px = 25 tiles exactly
                int px = t * 16 + l16;
                int y = px / 20, x = px - 20 * y;
                float4v acc = mfma_tile<3, MOS_LO>(lds + (y * 22 + x) * 16, voff, Ah, Al);
                int iy = gy0 - 2 + y, ix = gx0 - 2 + x;
                bool inb = (iy >= 0 && iy < IMG && ix >= 0 && ix < IMG);
                write_hl(lds + A_H + plOut + (y * 20 + x) * 16, A_LO, acc, inb);
            }
        }
        __syncthreads();

        // ========== L2: actA -> actB, region 18x18 (pair-tap K) ==========
        {
            short8v Ah[5], Al[5];
            build_afrags<5, false, 12>(w1, l16, g, Ah, Al);
            int voff[5];
            #pragma unroll
            for (int ks = 0; ks < 5; ++ks) voff[ks] = tapoff(2 * ks + (g >> 1), 20 * 16);
            const char* bbase0 = lds + A_H + (g & 1) * A_PL;
            const int plOut = (g >> 1) * B_PL + (g & 1) * 8;
            for (int t = wave; t < 21; t += 4) {           // 324 px -> 21 tiles (last partial)
                int px = t * 16 + l16;
                int cpx = min(px, 323);
                int y = cpx / 18, x = cpx - 18 * y;
                float4v acc = mfma_tile<5, A_LO>(bbase0 + (y * 20 + x) * 16, voff, Ah, Al);
                if (px < 324) {
                    int iy = gy0 - 1 + y, ix = gx0 - 1 + x;
                    bool inb = (iy >= 0 && iy < IMG && ix >= 0 && ix < IMG);
                    write_hl(lds + B_H + plOut + (y * 18 + x) * 16, B_LO, acc, inb);
                }
            }
        }
        __syncthreads();

        // ========== L3: actB -> f3 (s=0) / softmax+green (s=1), 16x16 ==========
        {
            short8v Ah[5], Al[5];
            build_afrags<5, false, 12>(w2, l16, g, Ah, Al);
            int voff[5];
            #pragma unroll
            for (int ks = 0; ks < 5; ++ks) voff[ks] = tapoff(2 * ks + (g >> 1), 18 * 16);
            const char* bbase0 = lds + B_H + (g & 1) * B_PL;
            #pragma unroll
            for (int tt = 0; tt < 4; ++tt) {
                int t = tt * 4 + wave;
                int px = t * 16 + l16;
                int y = px >> 4, x = px & 15;
                float4v acc = mfma_tile<5, B_LO>(bbase0 + (y * 18 + x) * 16, voff, Ah, Al);
                if (s == 0) {
                    #pragma unroll
                    for (int r = 0; r < 4; ++r) f3[tt][r] = fmaxf(acc[r], 0.f);
                } else {
                    // softmax over 12 real channels, split across k-groups g=0..2
                    // (rows 12-15 are exact zeros from zero A-rows; g==3 masked out)
                    float wv[4];
                    float m = 0.f;
                    #pragma unroll
                    for (int r = 0; r < 4; ++r) { wv[r] = fmaxf(acc[r], 0.f); m = fmaxf(m, wv[r]); }
                    if (g == 3) m = 0.f;
                    m = fmaxf(m, __shfl_xor(m, 16));
                    m = fmaxf(m, __shfl_xor(m, 32));
                    float d = 0.f, a0 = 0.f, a1 = 0.f;
                    if (g < 3) {
                        #pragma unroll
                        for (int r = 0; r < 4; ++r) {
                            float e = __expf(wv[r] - m);
                            d += e;
                            int ch = 4 * g + r;
                            if (ch < 6) a0 += e * f3[tt][r];
                            else        a1 += e * f3[tt][r];
                        }
                    }
                    d  += __shfl_xor(d, 16);  d  += __shfl_xor(d, 32);
                    a0 += __shfl_xor(a0, 16); a0 += __shfl_xor(a0, 32);
                    a1 += __shfl_xor(a1, 16); a1 += __shfl_xor(a1, 32);
                    float inv = 1.f / d;
                    int gy = gy0 + y, gx = gx0 + x;
                    float* gpl = out + (long long)(b * 3 + 1) * OPLANE;
                    if (g == 0) {        // (m0, g0) row; m0 reconstructed hi+lo (err ~1e-5)
                        const char* mp = lds + ((y + 3) * 22 + (x + 3)) * 16;
                        float m0 = bf2f(*reinterpret_cast<const unsigned short*>(mp))
                                 + bf2f(*reinterpret_cast<const unsigned short*>(mp + MOS_LO));
                        *reinterpret_cast<float2*>(&gpl[(long long)(2 * gy) * 1024 + 2 * gx]) =
                            make_float2(m0, a0 * inv);
                    } else if (g == 1) { // (g1, m3) row
                        const char* mp = lds + ((y + 3) * 22 + (x + 3)) * 16 + 6;
                        float m3 = bf2f(*reinterpret_cast<const unsigned short*>(mp))
                                 + bf2f(*reinterpret_cast<const unsigned short*>(mp + MOS_LO));
                        *reinterpret_cast<float2*>(&gpl[(long long)(2 * gy + 1) * 1024 + 2 * gx]) =
                            make_float2(a1 * inv, m3);
                    }
                }
            }
        }
        // next stack's L1 actA writes are safe: all waves passed the L2->L3 barrier
    }
}

// ---------------------------------------------------------------------------
// Stage 2: chroma 5x5 convs + interleave -> R and B planes. (unchanged, passed)
// chroma_input == 0 at (even,even) and (odd,odd) flat sites.
// ---------------------------------------------------------------------------
template <int PI, int PJ>
__device__ __forceinline__ float conv5(const float (&c1s)[18][18], const float (&c2s)[18][18],
                                       const float* __restrict__ w, int ly, int lx)
{
    float acc = 0.f;
    #pragma unroll
    for (int ky = 0; ky < 5; ++ky) {
        const int fy = PI + ky - 2;
        const int qy = (fy - (fy & 1)) / 2;
        const int ry = fy & 1;
        #pragma unroll
        for (int kx = 0; kx < 5; ++kx) {
            const int fx = PJ + kx - 2;
            const int qx = (fx - (fx & 1)) / 2;
            const int rx = fx & 1;
            if (ry == 0 && rx == 1)
                acc = fmaf(c1s[ly + qy][lx + qx], w[ky * 5 + kx], acc);
            else if (ry == 1 && rx == 0)
                acc = fmaf(c2s[ly + qy][lx + qx], w[ky * 5 + kx], acc);
        }
    }
    return acc;
}

__global__ __launch_bounds__(256) void demosaic_stage2(
    const float* __restrict__ mosaic,
    const float* gplane,
    const float* __restrict__ chw, const float* __restrict__ cvw, const float* __restrict__ cqw,
    float* out)
{
    __shared__ float c1s[18][18];
    __shared__ float c2s[18][18];

    const int tid = threadIdx.x;
    const int b   = blockIdx.z;
    const int qy0 = blockIdx.y * 16;
    const int qx0 = blockIdx.x * 16;

    const float* gpl = gplane + (long long)(b * 3 + 1) * OPLANE;

    for (int idx = tid; idx < 324; idx += 256) {
        int y = idx / 18, x = idx - y * 18;
        int gy = qy0 - 1 + y, gx = qx0 - 1 + x;
        float v1 = 0.f, v2 = 0.f;
        if (gy >= 0 && gy < IMG && gx >= 0 && gx < IMG) {
            float m1 = mosaic[((b * 4 + 1) * IMG + gy) * IMG + gx];
            float m2 = mosaic[((b * 4 + 2) * IMG + gy) * IMG + gx];
            float2 ta = *reinterpret_cast<const float2*>(&gpl[(long long)(2 * gy) * 1024 + 2 * gx]);
            float2 tb = *reinterpret_cast<const float2*>(&gpl[(long long)(2 * gy + 1) * 1024 + 2 * gx]);
            v1 = m1 - ta.y;
            v2 = m2 - tb.x;
        }
        c1s[y][x] = v1;
        c2s[y][x] = v2;
    }
    __syncthreads();

    const int ty = tid >> 4, tx = tid & 15;
    const int qy = qy0 + ty, qx = qx0 + tx;
    const int ly = ty + 1, lx = tx + 1;

    const float2 t0 = *reinterpret_cast<const float2*>(&gpl[(long long)(2 * qy) * 1024 + 2 * qx]);
    const float2 t1 = *reinterpret_cast<const float2*>(&gpl[(long long)(2 * qy + 1) * 1024 + 2 * qx]);
    const float m0 = t0.x, g0 = t0.y, g1 = t1.x, m3 = t1.y;
    const float m1 = mosaic[((b * 4 + 1) * IMG + qy) * IMG + qx];
    const float m2 = mosaic[((b * 4 + 2) * IMG + qy) * IMG + qx];

    const float ch_ee = conv5<0, 0>(c1s, c2s, chw, ly, lx);
    const float ch_oo = conv5<1, 1>(c1s, c2s, chw, ly, lx);
    const float cv_ee = conv5<0, 0>(c1s, c2s, cvw, ly, lx);
    const float cv_oo = conv5<1, 1>(c1s, c2s, cvw, ly, lx);
    const float cq_eo = conv5<0, 1>(c1s, c2s, cqw, ly, lx);
    const float cq_oe = conv5<1, 0>(c1s, c2s, cqw, ly, lx);

    const float r00 = ch_ee + m0, r01 = m1,         r10 = cq_oe + g1, r11 = cv_oo + m3;
    const float b00 = cv_ee + m0, b01 = cq_eo + g0, b10 = m2,         b11 = ch_oo + m3;

    const int ys = 2 * qy, xs = 2 * qx;
    float* outR = out + (long long)(b * 3 + 0) * OPLANE;
    float* outB = out + (long long)(b * 3 + 2) * OPLANE;

    *reinterpret_cast<float2*>(&outR[(long long)ys * 1024 + xs])       = make_float2(r00, r01);
    *reinterpret_cast<float2*>(&outR[(long long)(ys + 1) * 1024 + xs]) = make_float2(r10, r11);
    *reinterpret_cast<float2*>(&outB[(long long)ys * 1024 + xs])       = make_float2(b00, b01);
    *reinterpret_cast<float2*>(&outB[(long long)(ys + 1) * 1024 + xs]) = make_float2(b10, b11);
}

extern "C" void kernel_launch(void* const* d_in, const int* in_sizes, int n_in,
                              void* d_out, int out_size, void* d_ws, size_t ws_size,
                              hipStream_t stream)
{
    const float* mosaic = (const float*)d_in[0];
    const float* fw0 = (const float*)d_in[1];
    const float* fw1 = (const float*)d_in[2];
    const float* fw2 = (const float*)d_in[3];
    const float* ww0 = (const float*)d_in[4];
    const float* ww1 = (const float*)d_in[5];
    const float* ww2 = (const float*)d_in[6];
    const float* chw = (const float*)d_in[7];
    const float* cvw = (const float*)d_in[8];
    const float* cqw = (const float*)d_in[9];

    float* out = (float*)d_out;            // [8][3][1024][1024] fp32

    dim3 grid(IMG / 16, IMG / 16, 8);      // 32 x 32 x 8
    demosaic_stage1<<<grid, 256, 0, stream>>>(mosaic, fw0, fw1, fw2, ww0, ww1, ww2, out);
    demosaic_stage2<<<grid, 256, 0, stream>>>(mosaic, out, chw, cvw, cqw, out);
}

// Round 6
// 419.339 us; speedup vs baseline: 2.0949x; 1.4083x over previous
//
#include <hip/hip_runtime.h>
#include <hip/hip_bf16.h>

constexpr int IMG = 512;
constexpr long long OPLANE = 1024LL * 1024LL;   // one output plane (2H x 2W)

typedef __attribute__((ext_vector_type(8))) short   short8v;   // 8 bf16 (4 VGPR) MFMA frag
typedef __attribute__((ext_vector_type(4))) float   float4v;   // MFMA C/D frag
typedef __attribute__((ext_vector_type(4))) unsigned int uint4v;

// ---- LDS carve (bytes) ----
// mosaic [22][22][8] bf16: ch0-3 = hi, ch4-7 = lo (interleaved)        7744
// actA   hi[2][20][20][8] @A_H, lo @+A_LO                             25600
// actB   hi[2][18][18][8] @B_H, lo @+B_LO                             20736
#define A_H     7744
#define A_PL    6400
#define A_LO    12800
#define B_H     33344
#define B_PL    5184
#define B_LO    10368
#define LDS_BYTES 54080

// ---- weight-fragment workspace layout (per stack: 23552 B) ----
//  L1: [3ks][64lane]  16B (A1 frag, hi|lo interleaved)    3072
//  L2: [5ks][64lane]  32B (Ah frag | Al frag)            10240
//  L3: [5ks][64lane]  32B                                10240
#define WS_STACK 23552
#define WS_L2    3072
#define WS_L3    13312

__device__ __forceinline__ unsigned short f2bf(float v) {
    __hip_bfloat16 h = __float2bfloat16(v);
    return *reinterpret_cast<unsigned short*>(&h);
}
__device__ __forceinline__ float bf2f(unsigned short u) {
    __hip_bfloat16 h = *reinterpret_cast<__hip_bfloat16*>(&u);
    return __bfloat162float(h);
}

// byte offset in the activation array for conv tap t (3x3 raster), 0 for padded taps
__device__ __forceinline__ int tapoff(int t, int rowBytes) {
    if (t >= 9) return 0;
    int dy = t / 3;
    int dx = t - 3 * dy;
    return dy * rowBytes + dx * 16;
}

// ---------------------------------------------------------------------------
// Weight-fragment precompute: one tiny launch, writes d_ws.
// 128 threads: tid>>6 = stack, tid&63 = lane.
//  L1 (QUAD k-map): k=8g+e: tap=4ks+g, e<4 -> hi(ch=e), e>=4 -> lo(ch=e-4)
//  L2/L3 (PAIR):    k=8g+e: tap=2ks+(g>>1), ch=(g&1)*8+e ; Ah and Al frags
// A row = lane&15 = out-channel (rows >= 12 zero).
// ---------------------------------------------------------------------------
__global__ __launch_bounds__(128) void precompute_frags(
    const float* __restrict__ fw0, const float* __restrict__ fw1, const float* __restrict__ fw2,
    const float* __restrict__ ww0, const float* __restrict__ ww1, const float* __restrict__ ww2,
    char* __restrict__ ws)
{
    const int tid  = threadIdx.x;
    const int s    = tid >> 6;
    const int lane = tid & 63;
    const int row  = lane & 15;
    const int g    = lane >> 4;
    const float* w0 = s ? ww0 : fw0;
    const float* w1 = s ? ww1 : fw1;
    const float* w2 = s ? ww2 : fw2;
    char* base = ws + s * WS_STACK;

    // L1 quad-tap frags (hi|lo interleaved in one frag)
    for (int ks = 0; ks < 3; ++ks) {
        short8v a;
        int tap = 4 * ks + g;
        #pragma unroll
        for (int e = 0; e < 8; ++e) {
            int c = e & 3;
            bool valid = (row < 12) && (tap < 9);
            float v = valid ? w0[(row * 4 + c) * 9 + tap] : 0.f;
            unsigned short hs = f2bf(v);
            a[e] = (e < 4) ? (short)hs : (short)f2bf(v - bf2f(hs));
        }
        *reinterpret_cast<short8v*>(base + ks * 1024 + lane * 16) = a;
    }
    // L2 / L3 pair-tap frags (Ah | Al)
    for (int l = 0; l < 2; ++l) {
        const float* w = l ? w2 : w1;
        char* lb = base + (l ? WS_L3 : WS_L2);
        for (int ks = 0; ks < 5; ++ks) {
            short8v ah, al;
            int tap = 2 * ks + (g >> 1);
            #pragma unroll
            for (int e = 0; e < 8; ++e) {
                int ch = (g & 1) * 8 + e;
                bool valid = (row < 12) && (ch < 12) && (tap < 9);
                float v = valid ? w[(row * 12 + ch) * 9 + tap] : 0.f;
                unsigned short hs = f2bf(v);
                ah[e] = (short)hs;
                al[e] = (short)f2bf(v - bf2f(hs));
            }
            char* dst = lb + ks * 2048 + lane * 32;
            *reinterpret_cast<short8v*>(dst)      = ah;
            *reinterpret_cast<short8v*>(dst + 16) = al;
        }
    }
}

// Accumulate one 16(out-ch) x 16(px) tile, 3-term split (L2/L3 path).
template<int NK, int LO>
__device__ __forceinline__ float4v mfma_tile(const char* bbase, const int* voff,
                                             const short8v* Ah, const short8v* Al)
{
    float4v acc = {0.f, 0.f, 0.f, 0.f};
    #pragma unroll
    for (int ks = 0; ks < NK; ++ks) {
        const char* p = bbase + voff[ks];
        short8v bh = *reinterpret_cast<const short8v*>(p);
        short8v bl = *reinterpret_cast<const short8v*>(p + LO);
        acc = __builtin_amdgcn_mfma_f32_16x16x32_bf16(Ah[ks], bh, acc, 0, 0, 0);
        acc = __builtin_amdgcn_mfma_f32_16x16x32_bf16(Ah[ks], bl, acc, 0, 0, 0);
        acc = __builtin_amdgcn_mfma_f32_16x16x32_bf16(Al[ks], bh, acc, 0, 0, 0);
    }
    return acc;
}

// relu(+bound-zero), split to bf16 hi/lo, write 4 channels (8B hi + 8B lo)
__device__ __forceinline__ void write_hl(char* dst, int loOff, float4v acc, bool inb)
{
    unsigned long long hw = 0, lw = 0;
    #pragma unroll
    for (int r = 0; r < 4; ++r) {
        float v = inb ? fmaxf(acc[r], 0.f) : 0.f;
        unsigned short hs = f2bf(v);
        unsigned short ls = f2bf(v - bf2f(hs));
        hw |= (unsigned long long)hs << (16 * r);
        lw |= (unsigned long long)ls << (16 * r);
    }
    *reinterpret_cast<unsigned long long*>(dst) = hw;
    *reinterpret_cast<unsigned long long*>(dst + loOff) = lw;
}

// ---------------------------------------------------------------------------
// Stage 1 (MFMA): 3-layer conv stacks as hi/lo-split bf16 GEMMs.
// 16x16 tile / block, 256 threads. Weight frags pre-built in ws.
// ---------------------------------------------------------------------------
__global__ __launch_bounds__(256) void demosaic_stage1(
    const float* __restrict__ mosaic,
    const char* __restrict__ ws,
    float* __restrict__ out)
{
    __shared__ __align__(16) char lds[LDS_BYTES];
    const int tid  = threadIdx.x;
    const int lane = tid & 63;
    const int wave = tid >> 6;
    const int l16  = lane & 15;
    const int g    = lane >> 4;
    const int b    = blockIdx.z;
    const int gy0  = blockIdx.y * 16;
    const int gx0  = blockIdx.x * 16;

    // ---- stage mosaic (halo 3): [22][22][8] = hi ch0-3 | lo ch0-3 ----
    for (int idx = tid; idx < 484; idx += 256) {
        int y = idx / 22, x = idx - 22 * y;
        int gy = gy0 - 3 + y, gx = gx0 - 3 + x;
        bool inb = (gy >= 0 && gy < IMG && gx >= 0 && gx < IMG);
        unsigned short hs[4], ls[4];
        #pragma unroll
        for (int c = 0; c < 4; ++c) {
            float m = inb ? mosaic[((b * 4 + c) * IMG + gy) * IMG + gx] : 0.f;
            hs[c] = f2bf(m);
            ls[c] = f2bf(m - bf2f(hs[c]));
        }
        uint4v v = { (unsigned)hs[0] | ((unsigned)hs[1] << 16),
                     (unsigned)hs[2] | ((unsigned)hs[3] << 16),
                     (unsigned)ls[0] | ((unsigned)ls[1] << 16),
                     (unsigned)ls[2] | ((unsigned)ls[3] << 16) };
        *reinterpret_cast<uint4v*>(lds + (y * 22 + x) * 16) = v;
    }
    __syncthreads();

    float f3[4][4];           // interp-stack L3 outputs (4 ch per lane x 4 tiles)
    #pragma unroll 1
    for (int s = 0; s < 2; ++s) {
        const char* wsb = ws + s * WS_STACK;

        // ========== L1: mosaic(4ch) -> actA(12ch), 20x20, single-read 2-MFMA ==========
        {
            short8v A1[3];
            #pragma unroll
            for (int ks = 0; ks < 3; ++ks)
                A1[ks] = *reinterpret_cast<const short8v*>(wsb + ks * 1024 + lane * 16);
            int voff[3];
            #pragma unroll
            for (int ks = 0; ks < 3; ++ks) voff[ks] = tapoff(4 * ks + g, 22 * 16);
            const int plOut = (g >> 1) * A_PL + (g & 1) * 8;
            for (int t = wave; t < 25; t += 4) {           // 400 px = 25 tiles
                int px = t * 16 + l16;
                int y = px / 20, x = px - 20 * y;
                float4v acc = {0.f, 0.f, 0.f, 0.f};
                #pragma unroll
                for (int ks = 0; ks < 3; ++ks) {
                    short8v bb = *reinterpret_cast<const short8v*>(lds + (y * 22 + x) * 16 + voff[ks]);
                    short8v a2 = __builtin_shufflevector(A1[ks], A1[ks], 4, 5, 6, 7, 0, 1, 2, 3);
                    acc = __builtin_amdgcn_mfma_f32_16x16x32_bf16(A1[ks], bb, acc, 0, 0, 0);
                    acc = __builtin_amdgcn_mfma_f32_16x16x32_bf16(a2,     bb, acc, 0, 0, 0);
                }
                int iy = gy0 - 2 + y, ix = gx0 - 2 + x;
                bool inb = (iy >= 0 && iy < IMG && ix >= 0 && ix < IMG);
                write_hl(lds + A_H + plOut + (y * 20 + x) * 16, A_LO, acc, inb);
            }
        }
        __syncthreads();

        // ========== L2: actA -> actB, 18x18 (pair-tap K) ==========
        {
            short8v Ah[5], Al[5];
            #pragma unroll
            for (int ks = 0; ks < 5; ++ks) {
                const char* p = wsb + WS_L2 + ks * 2048 + lane * 32;
                Ah[ks] = *reinterpret_cast<const short8v*>(p);
                Al[ks] = *reinterpret_cast<const short8v*>(p + 16);
            }
            int voff[5];
            #pragma unroll
            for (int ks = 0; ks < 5; ++ks) voff[ks] = tapoff(2 * ks + (g >> 1), 20 * 16);
            const char* bbase0 = lds + A_H + (g & 1) * A_PL;
            const int plOut = (g >> 1) * B_PL + (g & 1) * 8;
            for (int t = wave; t < 21; t += 4) {           // 324 px -> 21 tiles (last partial)
                int px = t * 16 + l16;
                int cpx = min(px, 323);
                int y = cpx / 18, x = cpx - 18 * y;
                float4v acc = mfma_tile<5, A_LO>(bbase0 + (y * 20 + x) * 16, voff, Ah, Al);
                if (px < 324) {
                    int iy = gy0 - 1 + y, ix = gx0 - 1 + x;
                    bool inb = (iy >= 0 && iy < IMG && ix >= 0 && ix < IMG);
                    write_hl(lds + B_H + plOut + (y * 18 + x) * 16, B_LO, acc, inb);
                }
            }
        }
        __syncthreads();

        // ========== L3: actB -> f3 (s=0) / softmax+green (s=1), 16x16 ==========
        {
            short8v Ah[5], Al[5];
            #pragma unroll
            for (int ks = 0; ks < 5; ++ks) {
                const char* p = wsb + WS_L3 + ks * 2048 + lane * 32;
                Ah[ks] = *reinterpret_cast<const short8v*>(p);
                Al[ks] = *reinterpret_cast<const short8v*>(p + 16);
            }
            int voff[5];
            #pragma unroll
            for (int ks = 0; ks < 5; ++ks) voff[ks] = tapoff(2 * ks + (g >> 1), 18 * 16);
            const char* bbase0 = lds + B_H + (g & 1) * B_PL;
            #pragma unroll
            for (int tt = 0; tt < 4; ++tt) {
                int t = tt * 4 + wave;
                int px = t * 16 + l16;
                int y = px >> 4, x = px & 15;
                float4v acc = mfma_tile<5, B_LO>(bbase0 + (y * 18 + x) * 16, voff, Ah, Al);
                if (s == 0) {
                    #pragma unroll
                    for (int r = 0; r < 4; ++r) f3[tt][r] = fmaxf(acc[r], 0.f);
                } else {
                    // softmax over 12 real channels, split across k-groups g=0..2
                    float wv[4];
                    float m = 0.f;
                    #pragma unroll
                    for (int r = 0; r < 4; ++r) { wv[r] = fmaxf(acc[r], 0.f); m = fmaxf(m, wv[r]); }
                    if (g == 3) m = 0.f;
                    m = fmaxf(m, __shfl_xor(m, 16));
                    m = fmaxf(m, __shfl_xor(m, 32));
                    float d = 0.f, a0 = 0.f, a1 = 0.f;
                    if (g < 3) {
                        #pragma unroll
                        for (int r = 0; r < 4; ++r) {
                            float e = __expf(wv[r] - m);
                            d += e;
                            int ch = 4 * g + r;
                            if (ch < 6) a0 += e * f3[tt][r];
                            else        a1 += e * f3[tt][r];
                        }
                    }
                    d  += __shfl_xor(d, 16);  d  += __shfl_xor(d, 32);
                    a0 += __shfl_xor(a0, 16); a0 += __shfl_xor(a0, 32);
                    a1 += __shfl_xor(a1, 16); a1 += __shfl_xor(a1, 32);
                    float inv = 1.f / d;
                    int gy = gy0 + y, gx = gx0 + x;
                    float* gpl = out + (long long)(b * 3 + 1) * OPLANE;
                    if (g == 0) {        // (m0, g0) row; m0 = hi+lo (ch0 @+0, lo @+8)
                        const char* mp = lds + ((y + 3) * 22 + (x + 3)) * 16;
                        float m0 = bf2f(*reinterpret_cast<const unsigned short*>(mp))
                                 + bf2f(*reinterpret_cast<const unsigned short*>(mp + 8));
                        *reinterpret_cast<float2*>(&gpl[(long long)(2 * gy) * 1024 + 2 * gx]) =
                            make_float2(m0, a0 * inv);
                    } else if (g == 1) { // (g1, m3) row; m3 = hi @+6, lo @+14
                        const char* mp = lds + ((y + 3) * 22 + (x + 3)) * 16;
                        float m3 = bf2f(*reinterpret_cast<const unsigned short*>(mp + 6))
                                 + bf2f(*reinterpret_cast<const unsigned short*>(mp + 14));
                        *reinterpret_cast<float2*>(&gpl[(long long)(2 * gy + 1) * 1024 + 2 * gx]) =
                            make_float2(a1 * inv, m3);
                    }
                }
            }
        }
    }
}

// ---------------------------------------------------------------------------
// Stage 2: chroma 5x5 convs + interleave -> R and B planes. (unchanged, passed)
// ---------------------------------------------------------------------------
template <int PI, int PJ>
__device__ __forceinline__ float conv5(const float (&c1s)[18][18], const float (&c2s)[18][18],
                                       const float* __restrict__ w, int ly, int lx)
{
    float acc = 0.f;
    #pragma unroll
    for (int ky = 0; ky < 5; ++ky) {
        const int fy = PI + ky - 2;
        const int qy = (fy - (fy & 1)) / 2;
        const int ry = fy & 1;
        #pragma unroll
        for (int kx = 0; kx < 5; ++kx) {
            const int fx = PJ + kx - 2;
            const int qx = (fx - (fx & 1)) / 2;
            const int rx = fx & 1;
            if (ry == 0 && rx == 1)
                acc = fmaf(c1s[ly + qy][lx + qx], w[ky * 5 + kx], acc);
            else if (ry == 1 && rx == 0)
                acc = fmaf(c2s[ly + qy][lx + qx], w[ky * 5 + kx], acc);
        }
    }
    return acc;
}

__global__ __launch_bounds__(256) void demosaic_stage2(
    const float* __restrict__ mosaic,
    const float* gplane,
    const float* __restrict__ chw, const float* __restrict__ cvw, const float* __restrict__ cqw,
    float* out)
{
    __shared__ float c1s[18][18];
    __shared__ float c2s[18][18];

    const int tid = threadIdx.x;
    const int b   = blockIdx.z;
    const int qy0 = blockIdx.y * 16;
    const int qx0 = blockIdx.x * 16;

    const float* gpl = gplane + (long long)(b * 3 + 1) * OPLANE;

    for (int idx = tid; idx < 324; idx += 256) {
        int y = idx / 18, x = idx - y * 18;
        int gy = qy0 - 1 + y, gx = qx0 - 1 + x;
        float v1 = 0.f, v2 = 0.f;
        if (gy >= 0 && gy < IMG && gx >= 0 && gx < IMG) {
            float m1 = mosaic[((b * 4 + 1) * IMG + gy) * IMG + gx];
            float m2 = mosaic[((b * 4 + 2) * IMG + gy) * IMG + gx];
            float2 ta = *reinterpret_cast<const float2*>(&gpl[(long long)(2 * gy) * 1024 + 2 * gx]);
            float2 tb = *reinterpret_cast<const float2*>(&gpl[(long long)(2 * gy + 1) * 1024 + 2 * gx]);
            v1 = m1 - ta.y;
            v2 = m2 - tb.x;
        }
        c1s[y][x] = v1;
        c2s[y][x] = v2;
    }
    __syncthreads();

    const int ty = tid >> 4, tx = tid & 15;
    const int qy = qy0 + ty, qx = qx0 + tx;
    const int ly = ty + 1, lx = tx + 1;

    const float2 t0 = *reinterpret_cast<const float2*>(&gpl[(long long)(2 * qy) * 1024 + 2 * qx]);
    const float2 t1 = *reinterpret_cast<const float2*>(&gpl[(long long)(2 * qy + 1) * 1024 + 2 * qx]);
    const float m0 = t0.x, g0 = t0.y, g1 = t1.x, m3 = t1.y;
    const float m1 = mosaic[((b * 4 + 1) * IMG + qy) * IMG + qx];
    const float m2 = mosaic[((b * 4 + 2) * IMG + qy) * IMG + qx];

    const float ch_ee = conv5<0, 0>(c1s, c2s, chw, ly, lx);
    const float ch_oo = conv5<1, 1>(c1s, c2s, chw, ly, lx);
    const float cv_ee = conv5<0, 0>(c1s, c2s, cvw, ly, lx);
    const float cv_oo = conv5<1, 1>(c1s, c2s, cvw, ly, lx);
    const float cq_eo = conv5<0, 1>(c1s, c2s, cqw, ly, lx);
    const float cq_oe = conv5<1, 0>(c1s, c2s, cqw, ly, lx);

    const float r00 = ch_ee + m0, r01 = m1,         r10 = cq_oe + g1, r11 = cv_oo + m3;
    const float b00 = cv_ee + m0, b01 = cq_eo + g0, b10 = m2,         b11 = ch_oo + m3;

    const int ys = 2 * qy, xs = 2 * qx;
    float* outR = out + (long long)(b * 3 + 0) * OPLANE;
    float* outB = out + (long long)(b * 3 + 2) * OPLANE;

    *reinterpret_cast<float2*>(&outR[(long long)ys * 1024 + xs])       = make_float2(r00, r01);
    *reinterpret_cast<float2*>(&outR[(long long)(ys + 1) * 1024 + xs]) = make_float2(r10, r11);
    *reinterpret_cast<float2*>(&outB[(long long)ys * 1024 + xs])       = make_float2(b00, b01);
    *reinterpret_cast<float2*>(&outB[(long long)(ys + 1) * 1024 + xs]) = make_float2(b10, b11);
}

extern "C" void kernel_launch(void* const* d_in, const int* in_sizes, int n_in,
                              void* d_out, int out_size, void* d_ws, size_t ws_size,
                              hipStream_t stream)
{
    const float* mosaic = (const float*)d_in[0];
    const float* fw0 = (const float*)d_in[1];
    const float* fw1 = (const float*)d_in[2];
    const float* fw2 = (const float*)d_in[3];
    const float* ww0 = (const float*)d_in[4];
    const float* ww1 = (const float*)d_in[5];
    const float* ww2 = (const float*)d_in[6];
    const float* chw = (const float*)d_in[7];
    const float* cvw = (const float*)d_in[8];
    const float* cqw = (const float*)d_in[9];

    float* out = (float*)d_out;            // [8][3][1024][1024] fp32
    char*  ws  = (char*)d_ws;              // weight frags (47104 B)

    precompute_frags<<<1, 128, 0, stream>>>(fw0, fw1, fw2, ww0, ww1, ww2, ws);

    dim3 grid(IMG / 16, IMG / 16, 8);      // 32 x 32 x 8
    demosaic_stage1<<<grid, 256, 0, stream>>>(mosaic, ws, out);
    demosaic_stage2<<<grid, 256, 0, stream>>>(mosaic, out, chw, cvw, cqw, out);
}